// Round 9
// baseline (958.294 us; speedup 1.0000x reference)
//
#include <hip/hip_runtime.h>

#define L_SEQ 2048
#define BATCH 16
#define DDIM  1024
#define MDIM  (L_SEQ * BATCH)   // 32768
#define NDIM  (3 * DDIM)        // 3072
#define KDIM  DDIM              // 1024
#define CH    (BATCH * DDIM)    // 16384
#define NSEG  32
#define SEGL  64                // L_SEQ / NSEG

typedef __attribute__((ext_vector_type(8))) short short8;
typedef __attribute__((ext_vector_type(4))) float f32x4;

static __device__ __forceinline__ unsigned short f2bf(float f) {
  unsigned int u = __builtin_bit_cast(unsigned int, f);
  unsigned int lsb = (u >> 16) & 1u;
  u += 0x7fffu + lsb;
  return (unsigned short)(u >> 16);
}
static __device__ __forceinline__ float bf2f(unsigned short s) {
  unsigned int u = ((unsigned int)s) << 16;
  return __builtin_bit_cast(float, u);
}

static __device__ __forceinline__ void gll16(const void* g, void* l) {
  __builtin_amdgcn_global_load_lds(
      (const __attribute__((address_space(1))) unsigned int*)g,
      (__attribute__((address_space(3))) unsigned int*)l, 16, 0, 0);
}

// ---- converters ----------------------------------------------------------

__global__ void k_convert_x(const float4* __restrict__ x, ushort4* __restrict__ xb, int n4) {
  int i = blockIdx.x * blockDim.x + threadIdx.x;
  int stride = gridDim.x * blockDim.x;
  for (; i < n4; i += stride) {
    float4 v = x[i];
    ushort4 o;
    o.x = f2bf(v.x); o.y = f2bf(v.y); o.z = f2bf(v.z); o.w = f2bf(v.w);
    xb[i] = o;
  }
}

// Wb[n][k] = bf16( W[k][colmap(n)] ): regions {xt, f, r} -> contiguous col ranges
__global__ void k_convert_w(const float* __restrict__ w, unsigned short* __restrict__ wb) {
  int gid = blockIdx.x * 256 + threadIdx.x;   // 3072*1024 total
  int k = gid & (KDIM - 1);
  int n = gid >> 10;
  int col = (n < DDIM) ? 3 * n : (n < 2 * DDIM) ? 3 * (n - DDIM) + 1 : 3 * (n - 2 * DDIM) + 2;
  wb[gid] = f2bf(w[(size_t)k * NDIM + col]);
}

// ---- GEMM: 256x256 tile, 4 waves, per-wave 128x128 out, BK=32 ------------
// R8 post-mortem: invariant across 7 schedules is LDS READ AMPLIFICATION
// (2x4 wave grid -> 192 KB reads per BK=64-equivalent per CU). This kernel
// uses a 2x2 wave grid (amp 2x2): 64 reads (64 KB) per BK=32 tile per CU,
// strictly under the MFMA floor. 2 x 32KB LDS buffers, proven 4-slot
// permutation (0 conflicts), wrap-staging 1 tile ahead, vmcnt(0)+barrier/tile.

__global__ __launch_bounds__(256, 1) void k_gemm4w(
    const unsigned short* __restrict__ xb,   // [M][K] bf16
    const unsigned short* __restrict__ wb,   // [N][K] bf16
    const float* __restrict__ bias,          // [2d]
    unsigned short* __restrict__ xtb,        // [M][d] bf16
    unsigned short* __restrict__ fbuf,       // [M][d] bf16
    unsigned short* __restrict__ rbuf) {     // [M][d] bf16
  __shared__ char LDS[65536];   // 2 bufs x { A 256x64B | B 256x64B }
  char* LDSc = LDS;

  const int tid  = threadIdx.x;
  const int lane = tid & 63;
  const int wid  = tid >> 6;
  const int wr   = wid >> 1;     // 0..1 : 128-row half
  const int wc   = wid & 1;      // 0..1 : 128-col half

  // XCD-aware bijective swizzle: 1536 = 8 * 192
  int bid = blockIdx.x;
  int wg = (bid & 7) * 192 + (bid >> 3);
  int mt = wg / 12;
  int nt = wg - mt * 12;
  const int rowBase = mt * 256;
  const int colBase = nt * 256;

  // ds_read addresses (16B-slot permutation: phys = slot ^ ((row>>1)&3)),
  // 8 A-frag + 8 B-frag offsets, loop-invariant.
  const int l15 = lane & 15;
  const int sl  = lane >> 4;     // k-slot 0..3
  int aOff[8], bOff[8];
#pragma unroll
  for (int m = 0; m < 8; ++m) {
    int r = wr * 128 + m * 16 + l15;
    aOff[m] = r * 64 + ((sl ^ ((r >> 1) & 3)) << 4);
    int c = wc * 128 + m * 16 + l15;
    bOff[m] = 16384 + c * 64 + ((sl ^ ((c >> 1) & 3)) << 4);
  }

  // staging sources: thread t stages 16B units u = k*256 + tid, k=0..7
  // (k<4 -> A rows, k>=4 -> B rows); inverse slot permutation on source.
  const char* srcA[4];
  const char* srcB[4];
#pragma unroll
  for (int k = 0; k < 4; ++k) {
    int u = k * 256 + tid;
    int r = u >> 2;
    int s = (u & 3) ^ ((r >> 1) & 3);
    srcA[k] = (const char*)xb + (size_t)(rowBase + r) * 2048 + s * 16;
    srcB[k] = (const char*)wb + (size_t)(colBase + r) * 2048 + s * 16;
  }
  const int dstW = wid * 1024;   // wave-uniform base; HW adds lane*16

  f32x4 acc[8][8];
#pragma unroll
  for (int ii = 0; ii < 8; ++ii)
#pragma unroll
    for (int jj = 0; jj < 8; ++jj)
      acc[ii][jj] = (f32x4){0.f, 0.f, 0.f, 0.f};

  // prologue: stage tile 0 into buffer 0
#pragma unroll
  for (int k = 0; k < 4; ++k) {
    gll16(srcA[k], LDSc + k * 4096 + dstW);
    gll16(srcB[k], LDSc + 16384 + k * 4096 + dstW);
  }
  asm volatile("s_waitcnt vmcnt(0)" ::: "memory");
  __builtin_amdgcn_s_barrier();

  for (int t = 0; t < 32; ++t) {
    const char* bufC = LDSc + (t & 1) * 32768;
    char* bufS = LDSc + ((t + 1) & 1) * 32768;
    const int kb = ((t + 1) & 31) * 64;
    // stage tile t+1 (8 gll16), issued before compute
#pragma unroll
    for (int k = 0; k < 4; ++k) {
      gll16(srcA[k] + kb, bufS + k * 4096 + dstW);
      gll16(srcB[k] + kb, bufS + 16384 + k * 4096 + dstW);
    }
    __builtin_amdgcn_sched_barrier(0);
    // compute tile t: 16 ds_read_b128 + 64 MFMA (compiler-scheduled)
    short8 a[8], b[8];
#pragma unroll
    for (int n = 0; n < 8; ++n)
      b[n] = *(const short8*)(bufC + bOff[n]);
#pragma unroll
    for (int m = 0; m < 8; ++m) {
      a[m] = *(const short8*)(bufC + aOff[m]);
#pragma unroll
      for (int n = 0; n < 8; ++n)
        acc[m][n] = __builtin_amdgcn_mfma_f32_16x16x32_bf16(a[m], b[n], acc[m][n], 0, 0, 0);
    }
    asm volatile("s_waitcnt vmcnt(0)" ::: "memory");
    __builtin_amdgcn_s_barrier();
  }

  // epilogue: region 0 -> x_tilde (bf16), 1 -> forget, 2 -> reset
  const int region = colBase >> 10;
#pragma unroll
  for (int m = 0; m < 8; ++m) {
    int grow = rowBase + wr * 128 + m * 16 + (sl << 2);
#pragma unroll
    for (int n = 0; n < 8; ++n) {
      int gcol = colBase + wc * 128 + n * 16 + l15;
      f32x4 v = acc[m][n];
      if (region == 0) {
#pragma unroll
        for (int j = 0; j < 4; ++j)
          xtb[(size_t)(grow + j) * DDIM + gcol] = f2bf(v[j]);
      } else {
        float bv = bias[gcol - DDIM];
        unsigned short* dst = (region == 1) ? fbuf : rbuf;
        int lcol = gcol - (region << 10);
#pragma unroll
        for (int j = 0; j < 4; ++j) {
          float sg = 1.0f / (1.0f + __expf(-(v[j] + bv)));
          dst[(size_t)(grow + j) * DDIM + lcol] = f2bf(sg);
        }
      }
    }
  }
}

// ---- segmented scan (R5 versions — proven) -------------------------------
// pass 1: per (segment, channel-pair) affine state a = prod f, b = scan from 0

__global__ __launch_bounds__(256) void k_scan1(
    const unsigned short* __restrict__ fbuf,
    const unsigned short* __restrict__ xtb,
    float4* __restrict__ AB) {
  int chp = blockIdx.x * 256 + threadIdx.x;       // 0..8191 channel pairs
  int seg = blockIdx.y;
  size_t base = (size_t)seg * SEGL * CH + chp * 2;
  const unsigned int* fp = (const unsigned int*)(fbuf + base);
  const unsigned int* xp = (const unsigned int*)(xtb + base);
  float a0 = 1.f, a1 = 1.f, b0 = 0.f, b1 = 0.f;
#pragma unroll 8
  for (int s = 0; s < SEGL; ++s) {
    unsigned int fv = fp[(size_t)s * (CH / 2)];
    unsigned int xv = xp[(size_t)s * (CH / 2)];
    float f0 = bf2f((unsigned short)fv), f1 = bf2f((unsigned short)(fv >> 16));
    float x0 = bf2f((unsigned short)xv), x1 = bf2f((unsigned short)(xv >> 16));
    b0 = (b0 - x0) * f0 + x0;  a0 *= f0;
    b1 = (b1 - x1) * f1 + x1;  a1 *= f1;
  }
  AB[(size_t)seg * (CH / 2) + chp] = (float4){a0, b0, a1, b1};
}

// pass 2: scan 32 segment states per channel; emit per-segment c_in and c_last

__global__ __launch_bounds__(256) void k_scan2(
    const float* __restrict__ c0,
    const float4* __restrict__ AB,
    float* __restrict__ Cin,
    float* __restrict__ clast) {
  int chp = blockIdx.x * 256 + threadIdx.x;       // 0..8191
  float2 cc = ((const float2*)c0)[chp];
  float ca = cc.x, cb = cc.y;
#pragma unroll
  for (int s = 0; s < NSEG; ++s) {
    ((float2*)Cin)[(size_t)s * (CH / 2) + chp] = (float2){ca, cb};
    float4 ab = AB[(size_t)s * (CH / 2) + chp];
    ca = ca * ab.x + ab.y;
    cb = cb * ab.z + ab.w;
  }
  ((float2*)clast)[chp] = (float2){ca, cb};
}

// pass 3: recompute c within segment from c_in; emit h

__global__ __launch_bounds__(256) void k_scan3(
    const float* __restrict__ x,
    const unsigned short* __restrict__ fbuf,
    const unsigned short* __restrict__ xtb,
    const unsigned short* __restrict__ rbuf,
    const float* __restrict__ Cin,
    float* __restrict__ h) {
  int chp = blockIdx.x * 256 + threadIdx.x;
  int seg = blockIdx.y;
  float2 cc = ((const float2*)Cin)[(size_t)seg * (CH / 2) + chp];
  float ca = cc.x, cb = cc.y;
  size_t base = (size_t)seg * SEGL * CH + chp * 2;
  const unsigned int* fp = (const unsigned int*)(fbuf + base);
  const unsigned int* tp = (const unsigned int*)(xtb + base);
  const unsigned int* rp = (const unsigned int*)(rbuf + base);
  const float2* xp = (const float2*)(x + base);
  float2* hp = (float2*)(h + base);
#pragma unroll 4
  for (int s = 0; s < SEGL; ++s) {
    unsigned int fv = fp[(size_t)s * (CH / 2)];
    unsigned int tv = tp[(size_t)s * (CH / 2)];
    unsigned int rv = rp[(size_t)s * (CH / 2)];
    float2 xv = xp[(size_t)s * (CH / 2)];
    float f0 = bf2f((unsigned short)fv), f1 = bf2f((unsigned short)(fv >> 16));
    float t0 = bf2f((unsigned short)tv), t1 = bf2f((unsigned short)(tv >> 16));
    float r0 = bf2f((unsigned short)rv), r1 = bf2f((unsigned short)(rv >> 16));
    ca = (ca - t0) * f0 + t0;
    cb = (cb - t1) * f1 + t1;
    float e0 = __expf(-2.f * fabsf(ca));
    float e1 = __expf(-2.f * fabsf(cb));
    float g0 = copysignf((1.f - e0) / (1.f + e0), ca);
    float g1 = copysignf((1.f - e1) / (1.f + e1), cb);
    float h0 = (g0 - xv.x) * r0 + xv.x;
    float h1 = (g1 - xv.y) * r1 + xv.y;
    hp[(size_t)s * (CH / 2)] = (float2){h0, h1};
  }
}

// ---- launch --------------------------------------------------------------

extern "C" void kernel_launch(void* const* d_in, const int* in_sizes, int n_in,
                              void* d_out, int out_size, void* d_ws, size_t ws_size,
                              hipStream_t stream) {
  const float* x    = (const float*)d_in[0];
  const float* w    = (const float*)d_in[1];
  const float* bias = (const float*)d_in[2];
  const float* c0   = (const float*)d_in[3];
  float* out = (float*)d_out;
  char* ws = (char*)d_ws;

  // ws layout (207.6 MB total):
  //   [0, 6.29MB): wb (GEMM weights)  -- after GEMM, reused as AB (4MB) + Cin (2MB)
  unsigned short* wb   = (unsigned short*)(ws);
  float4*         AB   = (float4*)(ws);
  float*          Cin  = (float*)(ws + 4194304);
  unsigned short* xtb  = (unsigned short*)(ws + 6291456);
  unsigned short* fbuf = (unsigned short*)(ws + 73400320);
  unsigned short* rbuf = (unsigned short*)(ws + 140509184);
  // xb (bf16 x, 64MB) lives in d_out's h region (dead until pass 3 rewrites it)
  unsigned short* xb = (unsigned short*)d_out;

  k_convert_x<<<2048, 256, 0, stream>>>((const float4*)x, (ushort4*)xb, MDIM * KDIM / 4);
  k_convert_w<<<(NDIM * KDIM) / 256, 256, 0, stream>>>(w, wb);

  k_gemm4w<<<1536, 256, 0, stream>>>(xb, wb, bias, xtb, fbuf, rbuf);

  k_scan1<<<dim3(32, NSEG), 256, 0, stream>>>(fbuf, xtb, AB);
  k_scan2<<<32, 256, 0, stream>>>(c0, AB, Cin, out + (size_t)L_SEQ * CH);
  k_scan3<<<dim3(32, NSEG), 256, 0, stream>>>(x, fbuf, xtb, rbuf, Cin, out);
}

// Round 10
// 445.843 us; speedup vs baseline: 2.1494x; 2.1494x over previous
//
#include <hip/hip_runtime.h>

#define L_SEQ 2048
#define BATCH 16
#define DDIM  1024
#define MDIM  (L_SEQ * BATCH)   // 32768
#define NDIM  (3 * DDIM)        // 3072
#define KDIM  DDIM              // 1024
#define CH    (BATCH * DDIM)    // 16384
#define NSEG  32
#define SEGL  64                // L_SEQ / NSEG

typedef __attribute__((ext_vector_type(8))) short short8;
typedef __attribute__((ext_vector_type(4))) float f32x4;

static __device__ __forceinline__ unsigned short f2bf(float f) {
  unsigned int u = __builtin_bit_cast(unsigned int, f);
  unsigned int lsb = (u >> 16) & 1u;
  u += 0x7fffu + lsb;
  return (unsigned short)(u >> 16);
}
static __device__ __forceinline__ float bf2f(unsigned short s) {
  unsigned int u = ((unsigned int)s) << 16;
  return __builtin_bit_cast(float, u);
}

static __device__ __forceinline__ void gll16(const void* g, void* l) {
  __builtin_amdgcn_global_load_lds(
      (const __attribute__((address_space(1))) unsigned int*)g,
      (__attribute__((address_space(3))) unsigned int*)l, 16, 0, 0);
}

// ---- converters ----------------------------------------------------------

__global__ void k_convert_x(const float4* __restrict__ x, ushort4* __restrict__ xb, int n4) {
  int i = blockIdx.x * blockDim.x + threadIdx.x;
  int stride = gridDim.x * blockDim.x;
  for (; i < n4; i += stride) {
    float4 v = x[i];
    ushort4 o;
    o.x = f2bf(v.x); o.y = f2bf(v.y); o.z = f2bf(v.z); o.w = f2bf(v.w);
    xb[i] = o;
  }
}

// Wb[n][k] = bf16( W[k][colmap(n)] ): regions {xt, f, r} -> contiguous col ranges
__global__ void k_convert_w(const float* __restrict__ w, unsigned short* __restrict__ wb) {
  int gid = blockIdx.x * 256 + threadIdx.x;   // 3072*1024 total
  int k = gid & (KDIM - 1);
  int n = gid >> 10;
  int col = (n < DDIM) ? 3 * n : (n < 2 * DDIM) ? 3 * (n - DDIM) + 1 : 3 * (n - 2 * DDIM) + 2;
  wb[gid] = f2bf(w[(size_t)k * NDIM + col]);
}

// ---- GEMM: 256x128 tile, BK=64, 8 waves, 3-buf depth-2 counted-vmcnt -----
// R9 post-mortem: the binder is exposed memory latency at per-tile sync
// points. This structure gives {depth-2 staging + counted vmcnt(6) (never
// drains to 0) + exactly ONE barrier per BK=64 tile}: 3 LDS buffers x 48KB
// (A_kb0 16K | A_kb1 16K | B_kb0 8K | B_kb1 8K), each sub-tile rows x 64B
// with the proven 4-slot permutation (slot ^ ((row>>1)&3), 0 conflicts).
// WAR: stage at T targets buf[(T+2)%3], last read at T-1, covered by T-1's
// barrier. Data arrival: vmcnt(6) at T drains T+1's 6 loads; barrier makes
// it block-wide. Per-wave output 128x32 -> acc = 64 VGPR (no spill).

__global__ __launch_bounds__(512, 1) void k_gemm(
    const unsigned short* __restrict__ xb,   // [M][K] bf16
    const unsigned short* __restrict__ wb,   // [N][K] bf16
    const float* __restrict__ bias,          // [2d]
    unsigned short* __restrict__ xtb,        // [M][d] bf16
    unsigned short* __restrict__ fbuf,       // [M][d] bf16
    unsigned short* __restrict__ rbuf) {     // [M][d] bf16
  __shared__ char LDS[147456];   // 3 bufs x 48KB
  char* LDSc = LDS;

  const int tid  = threadIdx.x;
  const int lane = tid & 63;
  const int wid  = tid >> 6;
  const int wr   = wid >> 2;     // 0..1 : 128-row half
  const int wc   = wid & 3;      // 0..3 : 32-col quarter

  // XCD-aware bijective swizzle: 3072 = 8 * 384
  int bid = blockIdx.x;
  int wg = (bid & 7) * 384 + (bid >> 3);
  int mt = wg / 24;              // 0..127
  int nt = wg - mt * 24;         // 0..23
  const int rowBase = mt * 256;
  const int colBase = nt * 128;

  // ds_read offsets (within a 48KB buffer), proven slot permutation.
  const int l15 = lane & 15;
  const int sl  = lane >> 4;     // 16B k-slot 0..3
  int aOff[8], bOff[2];
#pragma unroll
  for (int m = 0; m < 8; ++m) {
    int r = wr * 128 + m * 16 + l15;
    aOff[m] = r * 64 + ((sl ^ ((r >> 1) & 3)) << 4);          // A_kb0; kb1 at +16384
  }
#pragma unroll
  for (int n = 0; n < 2; ++n) {
    int c = wc * 32 + n * 16 + l15;
    bOff[n] = 32768 + c * 64 + ((sl ^ ((c >> 1) & 3)) << 4);  // B_kb0; kb1 at +8192
  }

  // staging sources (inverse slot permutation on global source, linear LDS dst)
  const int rA0 = tid >> 2, rA1 = 128 + (tid >> 2);
  const int sA0 = (tid & 3) ^ ((rA0 >> 1) & 3);
  const int sA1 = (tid & 3) ^ ((rA1 >> 1) & 3);
  const char* srcA0 = (const char*)xb + (size_t)(rowBase + rA0) * 2048 + sA0 * 16;
  const char* srcA1 = (const char*)xb + (size_t)(rowBase + rA1) * 2048 + sA1 * 16;
  const char* srcB0 = (const char*)wb + (size_t)(colBase + rA0) * 2048 + sA0 * 16;
  const int dstW = wid * 1024;   // wave-uniform base; HW adds lane*16

  f32x4 acc[8][2];
#pragma unroll
  for (int ii = 0; ii < 8; ++ii)
#pragma unroll
    for (int jj = 0; jj < 2; ++jj)
      acc[ii][jj] = (f32x4){0.f, 0.f, 0.f, 0.f};

  // prologue: stage tiles 0 (buf0) and 1 (buf1)
#pragma unroll
  for (int u = 0; u < 2; ++u) {
    char* b = LDSc + u * 49152;
    gll16(srcA0 + u * 128,      b +         dstW);
    gll16(srcA1 + u * 128,      b +  8192 + dstW);
    gll16(srcA0 + u * 128 + 64, b + 16384 + dstW);
    gll16(srcA1 + u * 128 + 64, b + 24576 + dstW);
    gll16(srcB0 + u * 128,      b + 32768 + dstW);
    gll16(srcB0 + u * 128 + 64, b + 40960 + dstW);
  }
  asm volatile("s_waitcnt vmcnt(6)" ::: "memory");   // tile 0 landed; tile 1 in flight
  __builtin_amdgcn_s_barrier();

  short8 a0, a1, a2, a3, a4, a5, a6, a7, b0, b1;

#pragma unroll
  for (int t = 0; t < 16; ++t) {
    const char* bufC = LDSc + (t % 3) * 49152;
    char*       bufS = LDSc + ((t + 2) % 3) * 49152;
    const int stA = ((t + 2) & 15) * 128;
    // stage tile t+2 (6 gll16), issued before compute
    gll16(srcA0 + stA,      bufS +         dstW);
    gll16(srcA1 + stA,      bufS +  8192 + dstW);
    gll16(srcA0 + stA + 64, bufS + 16384 + dstW);
    gll16(srcA1 + stA + 64, bufS + 24576 + dstW);
    gll16(srcB0 + stA,      bufS + 32768 + dstW);
    gll16(srcB0 + stA + 64, bufS + 40960 + dstW);
    __builtin_amdgcn_sched_barrier(0);
    // ---- kstep 0 (kb0 sub-tiles) ----
    a0 = *(const short8*)(bufC + aOff[0]);
    a1 = *(const short8*)(bufC + aOff[1]);
    a2 = *(const short8*)(bufC + aOff[2]);
    a3 = *(const short8*)(bufC + aOff[3]);
    a4 = *(const short8*)(bufC + aOff[4]);
    a5 = *(const short8*)(bufC + aOff[5]);
    a6 = *(const short8*)(bufC + aOff[6]);
    a7 = *(const short8*)(bufC + aOff[7]);
    b0 = *(const short8*)(bufC + bOff[0]);
    b1 = *(const short8*)(bufC + bOff[1]);
    __builtin_amdgcn_s_setprio(1);
    acc[0][0] = __builtin_amdgcn_mfma_f32_16x16x32_bf16(a0, b0, acc[0][0], 0, 0, 0);
    acc[0][1] = __builtin_amdgcn_mfma_f32_16x16x32_bf16(a0, b1, acc[0][1], 0, 0, 0);
    acc[1][0] = __builtin_amdgcn_mfma_f32_16x16x32_bf16(a1, b0, acc[1][0], 0, 0, 0);
    acc[1][1] = __builtin_amdgcn_mfma_f32_16x16x32_bf16(a1, b1, acc[1][1], 0, 0, 0);
    acc[2][0] = __builtin_amdgcn_mfma_f32_16x16x32_bf16(a2, b0, acc[2][0], 0, 0, 0);
    acc[2][1] = __builtin_amdgcn_mfma_f32_16x16x32_bf16(a2, b1, acc[2][1], 0, 0, 0);
    acc[3][0] = __builtin_amdgcn_mfma_f32_16x16x32_bf16(a3, b0, acc[3][0], 0, 0, 0);
    acc[3][1] = __builtin_amdgcn_mfma_f32_16x16x32_bf16(a3, b1, acc[3][1], 0, 0, 0);
    acc[4][0] = __builtin_amdgcn_mfma_f32_16x16x32_bf16(a4, b0, acc[4][0], 0, 0, 0);
    acc[4][1] = __builtin_amdgcn_mfma_f32_16x16x32_bf16(a4, b1, acc[4][1], 0, 0, 0);
    acc[5][0] = __builtin_amdgcn_mfma_f32_16x16x32_bf16(a5, b0, acc[5][0], 0, 0, 0);
    acc[5][1] = __builtin_amdgcn_mfma_f32_16x16x32_bf16(a5, b1, acc[5][1], 0, 0, 0);
    acc[6][0] = __builtin_amdgcn_mfma_f32_16x16x32_bf16(a6, b0, acc[6][0], 0, 0, 0);
    acc[6][1] = __builtin_amdgcn_mfma_f32_16x16x32_bf16(a6, b1, acc[6][1], 0, 0, 0);
    acc[7][0] = __builtin_amdgcn_mfma_f32_16x16x32_bf16(a7, b0, acc[7][0], 0, 0, 0);
    acc[7][1] = __builtin_amdgcn_mfma_f32_16x16x32_bf16(a7, b1, acc[7][1], 0, 0, 0);
    __builtin_amdgcn_s_setprio(0);
    // ---- kstep 1 (kb1 sub-tiles) ----
    a0 = *(const short8*)(bufC + 16384 + aOff[0]);
    a1 = *(const short8*)(bufC + 16384 + aOff[1]);
    a2 = *(const short8*)(bufC + 16384 + aOff[2]);
    a3 = *(const short8*)(bufC + 16384 + aOff[3]);
    a4 = *(const short8*)(bufC + 16384 + aOff[4]);
    a5 = *(const short8*)(bufC + 16384 + aOff[5]);
    a6 = *(const short8*)(bufC + 16384 + aOff[6]);
    a7 = *(const short8*)(bufC + 16384 + aOff[7]);
    b0 = *(const short8*)(bufC + 8192 + bOff[0]);
    b1 = *(const short8*)(bufC + 8192 + bOff[1]);
    __builtin_amdgcn_s_setprio(1);
    acc[0][0] = __builtin_amdgcn_mfma_f32_16x16x32_bf16(a0, b0, acc[0][0], 0, 0, 0);
    acc[0][1] = __builtin_amdgcn_mfma_f32_16x16x32_bf16(a0, b1, acc[0][1], 0, 0, 0);
    acc[1][0] = __builtin_amdgcn_mfma_f32_16x16x32_bf16(a1, b0, acc[1][0], 0, 0, 0);
    acc[1][1] = __builtin_amdgcn_mfma_f32_16x16x32_bf16(a1, b1, acc[1][1], 0, 0, 0);
    acc[2][0] = __builtin_amdgcn_mfma_f32_16x16x32_bf16(a2, b0, acc[2][0], 0, 0, 0);
    acc[2][1] = __builtin_amdgcn_mfma_f32_16x16x32_bf16(a2, b1, acc[2][1], 0, 0, 0);
    acc[3][0] = __builtin_amdgcn_mfma_f32_16x16x32_bf16(a3, b0, acc[3][0], 0, 0, 0);
    acc[3][1] = __builtin_amdgcn_mfma_f32_16x16x32_bf16(a3, b1, acc[3][1], 0, 0, 0);
    acc[4][0] = __builtin_amdgcn_mfma_f32_16x16x32_bf16(a4, b0, acc[4][0], 0, 0, 0);
    acc[4][1] = __builtin_amdgcn_mfma_f32_16x16x32_bf16(a4, b1, acc[4][1], 0, 0, 0);
    acc[5][0] = __builtin_amdgcn_mfma_f32_16x16x32_bf16(a5, b0, acc[5][0], 0, 0, 0);
    acc[5][1] = __builtin_amdgcn_mfma_f32_16x16x32_bf16(a5, b1, acc[5][1], 0, 0, 0);
    acc[6][0] = __builtin_amdgcn_mfma_f32_16x16x32_bf16(a6, b0, acc[6][0], 0, 0, 0);
    acc[6][1] = __builtin_amdgcn_mfma_f32_16x16x32_bf16(a6, b1, acc[6][1], 0, 0, 0);
    acc[7][0] = __builtin_amdgcn_mfma_f32_16x16x32_bf16(a7, b0, acc[7][0], 0, 0, 0);
    acc[7][1] = __builtin_amdgcn_mfma_f32_16x16x32_bf16(a7, b1, acc[7][1], 0, 0, 0);
    __builtin_amdgcn_s_setprio(0);
    // single sync per tile: counted wait (T+1 landed, T+2 in flight) + barrier
    asm volatile("s_waitcnt vmcnt(6)" ::: "memory");
    __builtin_amdgcn_s_barrier();
  }

  // epilogue: region 0 -> x_tilde (bf16), 1 -> forget, 2 -> reset
  const int region = colBase >> 10;
#pragma unroll
  for (int m = 0; m < 8; ++m) {
    int grow = rowBase + wr * 128 + m * 16 + (sl << 2);
#pragma unroll
    for (int n = 0; n < 2; ++n) {
      int gcol = colBase + wc * 32 + n * 16 + l15;
      f32x4 v = acc[m][n];
      if (region == 0) {
#pragma unroll
        for (int j = 0; j < 4; ++j)
          xtb[(size_t)(grow + j) * DDIM + gcol] = f2bf(v[j]);
      } else {
        float bv = bias[gcol - DDIM];
        unsigned short* dst = (region == 1) ? fbuf : rbuf;
        int lcol = gcol - (region << 10);
#pragma unroll
        for (int j = 0; j < 4; ++j) {
          float sg = 1.0f / (1.0f + __expf(-(v[j] + bv)));
          dst[(size_t)(grow + j) * DDIM + lcol] = f2bf(sg);
        }
      }
    }
  }
}

// ---- segmented scan (R5 versions — proven) -------------------------------
// pass 1: per (segment, channel-pair) affine state a = prod f, b = scan from 0

__global__ __launch_bounds__(256) void k_scan1(
    const unsigned short* __restrict__ fbuf,
    const unsigned short* __restrict__ xtb,
    float4* __restrict__ AB) {
  int chp = blockIdx.x * 256 + threadIdx.x;       // 0..8191 channel pairs
  int seg = blockIdx.y;
  size_t base = (size_t)seg * SEGL * CH + chp * 2;
  const unsigned int* fp = (const unsigned int*)(fbuf + base);
  const unsigned int* xp = (const unsigned int*)(xtb + base);
  float a0 = 1.f, a1 = 1.f, b0 = 0.f, b1 = 0.f;
#pragma unroll 8
  for (int s = 0; s < SEGL; ++s) {
    unsigned int fv = fp[(size_t)s * (CH / 2)];
    unsigned int xv = xp[(size_t)s * (CH / 2)];
    float f0 = bf2f((unsigned short)fv), f1 = bf2f((unsigned short)(fv >> 16));
    float x0 = bf2f((unsigned short)xv), x1 = bf2f((unsigned short)(xv >> 16));
    b0 = (b0 - x0) * f0 + x0;  a0 *= f0;
    b1 = (b1 - x1) * f1 + x1;  a1 *= f1;
  }
  AB[(size_t)seg * (CH / 2) + chp] = (float4){a0, b0, a1, b1};
}

// pass 2: scan 32 segment states per channel; emit per-segment c_in and c_last

__global__ __launch_bounds__(256) void k_scan2(
    const float* __restrict__ c0,
    const float4* __restrict__ AB,
    float* __restrict__ Cin,
    float* __restrict__ clast) {
  int chp = blockIdx.x * 256 + threadIdx.x;       // 0..8191
  float2 cc = ((const float2*)c0)[chp];
  float ca = cc.x, cb = cc.y;
#pragma unroll
  for (int s = 0; s < NSEG; ++s) {
    ((float2*)Cin)[(size_t)s * (CH / 2) + chp] = (float2){ca, cb};
    float4 ab = AB[(size_t)s * (CH / 2) + chp];
    ca = ca * ab.x + ab.y;
    cb = cb * ab.z + ab.w;
  }
  ((float2*)clast)[chp] = (float2){ca, cb};
}

// pass 3: recompute c within segment from c_in; emit h

__global__ __launch_bounds__(256) void k_scan3(
    const float* __restrict__ x,
    const unsigned short* __restrict__ fbuf,
    const unsigned short* __restrict__ xtb,
    const unsigned short* __restrict__ rbuf,
    const float* __restrict__ Cin,
    float* __restrict__ h) {
  int chp = blockIdx.x * 256 + threadIdx.x;
  int seg = blockIdx.y;
  float2 cc = ((const float2*)Cin)[(size_t)seg * (CH / 2) + chp];
  float ca = cc.x, cb = cc.y;
  size_t base = (size_t)seg * SEGL * CH + chp * 2;
  const unsigned int* fp = (const unsigned int*)(fbuf + base);
  const unsigned int* tp = (const unsigned int*)(xtb + base);
  const unsigned int* rp = (const unsigned int*)(rbuf + base);
  const float2* xp = (const float2*)(x + base);
  float2* hp = (float2*)(h + base);
#pragma unroll 4
  for (int s = 0; s < SEGL; ++s) {
    unsigned int fv = fp[(size_t)s * (CH / 2)];
    unsigned int tv = tp[(size_t)s * (CH / 2)];
    unsigned int rv = rp[(size_t)s * (CH / 2)];
    float2 xv = xp[(size_t)s * (CH / 2)];
    float f0 = bf2f((unsigned short)fv), f1 = bf2f((unsigned short)(fv >> 16));
    float t0 = bf2f((unsigned short)tv), t1 = bf2f((unsigned short)(tv >> 16));
    float r0 = bf2f((unsigned short)rv), r1 = bf2f((unsigned short)(rv >> 16));
    ca = (ca - t0) * f0 + t0;
    cb = (cb - t1) * f1 + t1;
    float e0 = __expf(-2.f * fabsf(ca));
    float e1 = __expf(-2.f * fabsf(cb));
    float g0 = copysignf((1.f - e0) / (1.f + e0), ca);
    float g1 = copysignf((1.f - e1) / (1.f + e1), cb);
    float h0 = (g0 - xv.x) * r0 + xv.x;
    float h1 = (g1 - xv.y) * r1 + xv.y;
    hp[(size_t)s * (CH / 2)] = (float2){h0, h1};
  }
}

// ---- launch --------------------------------------------------------------

extern "C" void kernel_launch(void* const* d_in, const int* in_sizes, int n_in,
                              void* d_out, int out_size, void* d_ws, size_t ws_size,
                              hipStream_t stream) {
  const float* x    = (const float*)d_in[0];
  const float* w    = (const float*)d_in[1];
  const float* bias = (const float*)d_in[2];
  const float* c0   = (const float*)d_in[3];
  float* out = (float*)d_out;
  char* ws = (char*)d_ws;

  // ws layout (207.6 MB total):
  //   [0, 6.29MB): wb (GEMM weights)  -- after GEMM, reused as AB (4MB) + Cin (2MB)
  unsigned short* wb   = (unsigned short*)(ws);
  float4*         AB   = (float4*)(ws);
  float*          Cin  = (float*)(ws + 4194304);
  unsigned short* xtb  = (unsigned short*)(ws + 6291456);
  unsigned short* fbuf = (unsigned short*)(ws + 73400320);
  unsigned short* rbuf = (unsigned short*)(ws + 140509184);
  // xb (bf16 x, 64MB) lives in d_out's h region (dead until pass 3 rewrites it)
  unsigned short* xb = (unsigned short*)d_out;

  k_convert_x<<<2048, 256, 0, stream>>>((const float4*)x, (ushort4*)xb, MDIM * KDIM / 4);
  k_convert_w<<<(NDIM * KDIM) / 256, 256, 0, stream>>>(w, wb);

  k_gemm<<<3072, 512, 0, stream>>>(xb, wb, bias, xtb, fbuf, rbuf);

  k_scan1<<<dim3(32, NSEG), 256, 0, stream>>>(fbuf, xtb, AB);
  k_scan2<<<32, 256, 0, stream>>>(c0, AB, Cin, out + (size_t)L_SEQ * CH);
  k_scan3<<<dim3(32, NSEG), 256, 0, stream>>>(x, fbuf, xtb, rbuf, Cin, out);
}

// Round 11
// 405.841 us; speedup vs baseline: 2.3613x; 1.0986x over previous
//
#include <hip/hip_runtime.h>

#define L_SEQ 2048
#define BATCH 16
#define DDIM  1024
#define MDIM  (L_SEQ * BATCH)   // 32768
#define NDIM  (3 * DDIM)        // 3072
#define KDIM  DDIM              // 1024
#define CH    (BATCH * DDIM)    // 16384
#define NSEG  32
#define SEGL  64                // L_SEQ / NSEG

typedef __attribute__((ext_vector_type(8))) short short8;
typedef __attribute__((ext_vector_type(4))) float f32x4;

static __device__ __forceinline__ unsigned short f2bf(float f) {
  unsigned int u = __builtin_bit_cast(unsigned int, f);
  unsigned int lsb = (u >> 16) & 1u;
  u += 0x7fffu + lsb;
  return (unsigned short)(u >> 16);
}
static __device__ __forceinline__ float bf2f(unsigned short s) {
  unsigned int u = ((unsigned int)s) << 16;
  return __builtin_bit_cast(float, u);
}

static __device__ __forceinline__ void gll16(const void* g, void* l) {
  __builtin_amdgcn_global_load_lds(
      (const __attribute__((address_space(1))) unsigned int*)g,
      (__attribute__((address_space(3))) unsigned int*)l, 16, 0, 0);
}

// ---- converters ----------------------------------------------------------

__global__ void k_convert_x(const float4* __restrict__ x, ushort4* __restrict__ xb, int n4) {
  int i = blockIdx.x * blockDim.x + threadIdx.x;
  int stride = gridDim.x * blockDim.x;
  for (; i < n4; i += stride) {
    float4 v = x[i];
    ushort4 o;
    o.x = f2bf(v.x); o.y = f2bf(v.y); o.z = f2bf(v.z); o.w = f2bf(v.w);
    xb[i] = o;
  }
}

// Wb[n][k] = bf16( W[k][colmap(n)] ): regions {xt, f, r} -> contiguous col ranges
__global__ void k_convert_w(const float* __restrict__ w, unsigned short* __restrict__ wb) {
  int gid = blockIdx.x * 256 + threadIdx.x;   // 3072*1024 total
  int k = gid & (KDIM - 1);
  int n = gid >> 10;
  int col = (n < DDIM) ? 3 * n : (n < 2 * DDIM) ? 3 * (n - DDIM) + 1 : 3 * (n - 2 * DDIM) + 2;
  wb[gid] = f2bf(w[(size_t)k * NDIM + col]);
}

// ---- GEMM: 256x256, BK=64, 8 waves, m201-discipline 4-phase schedule -----
// LDS 160KB: A dbuf 2x32KB at 0, B tbuf 3x32KB at 65536. Each 32KB buffer =
// {kb0: 256x64B, kb1: 256x64B} sub-buffers with the proven 4-slot permutation
// (slot ^ ((row>>1)&3); measured 0 conflicts R3-R10).
// Phase = {ds_reads; 2 gll16; s_barrier; lgkmcnt(0); setprio1; 16 MFMA;
// setprio0; s_barrier} -- the barrier wait absorbs ds_read latency so the
// MFMA cluster runs unbroken (m201 mechanism).
// Slack: A(T+1) staged at T.P0-P1 (needed T+1.P0, ~3 phases later);
// B(T+2) staged at T.P2-P3 (needed T+2.P0, ~6 phases later).
// vmcnt(4) once per tile at P3: FIFO = [B(T+1) 4, A(T+1) 4, B(T+2) 4] ->
// leaves exactly B(T+2) outstanding, proves A(T+1)+B(T+1) landed. Never 0.

__global__ __launch_bounds__(512, 1) void k_gemm256(
    const unsigned short* __restrict__ xb,   // [M][K] bf16
    const unsigned short* __restrict__ wb,   // [N][K] bf16
    const float* __restrict__ bias,          // [2d]
    unsigned short* __restrict__ xtb,        // [M][d] bf16
    unsigned short* __restrict__ fbuf,       // [M][d] bf16
    unsigned short* __restrict__ rbuf) {     // [M][d] bf16
  __shared__ char LDS[163840];
  char* LDSc = LDS;

  const int tid  = threadIdx.x;
  const int lane = tid & 63;
  const int wid  = tid >> 6;
  const int wr   = wid >> 2;     // 0..1 : 128-row half
  const int wc   = wid & 3;      // 0..3 : 64-col quarter

  // XCD-aware bijective swizzle: 1536 = 8 * 192
  int bid = blockIdx.x;
  int wg = (bid & 7) * 192 + (bid >> 3);
  int mt = wg / 12;
  int nt = wg - mt * 12;
  const int rowBase = mt * 256;
  const int colBase = nt * 256;

  // ds_read offsets (within 16KB sub-buffer), proven slot permutation.
  const int l15 = lane & 15;
  const int sl  = lane >> 4;
  int aOff[8], bOff[4];
#pragma unroll
  for (int m = 0; m < 8; ++m) {
    int r = wr * 128 + m * 16 + l15;
    aOff[m] = r * 64 + ((sl ^ ((r >> 1) & 3)) << 4);
  }
#pragma unroll
  for (int n = 0; n < 4; ++n) {
    int c = wc * 64 + n * 16 + l15;
    bOff[n] = c * 64 + ((sl ^ ((c >> 1) & 3)) << 4);
  }

  // staging sources (inverse slot permutation on global source, linear LDS dst)
  const int r0s = tid >> 2, r1s = 128 + (tid >> 2);
  const int s0 = (tid & 3) ^ ((r0s >> 1) & 3);
  const int s1 = (tid & 3) ^ ((r1s >> 1) & 3);
  const char* srcA0 = (const char*)xb + (size_t)(rowBase + r0s) * 2048 + s0 * 16;
  const char* srcA1 = (const char*)xb + (size_t)(rowBase + r1s) * 2048 + s1 * 16;
  const char* srcB0 = (const char*)wb + (size_t)(colBase + r0s) * 2048 + s0 * 16;
  const char* srcB1 = (const char*)wb + (size_t)(colBase + r1s) * 2048 + s1 * 16;
  const int dstW = wid * 1024;

  f32x4 acc[8][4];
#pragma unroll
  for (int ii = 0; ii < 8; ++ii)
#pragma unroll
    for (int jj = 0; jj < 4; ++jj)
      acc[ii][jj] = (f32x4){0.f, 0.f, 0.f, 0.f};

  // prologue: A(0)->Abuf0, B(0)->Bbuf0, B(1)->Bbuf1   (12 gll16)
  gll16(srcA0,       LDSc + dstW);
  gll16(srcA1,       LDSc +  8192 + dstW);
  gll16(srcA0 + 64,  LDSc + 16384 + dstW);
  gll16(srcA1 + 64,  LDSc + 24576 + dstW);
  gll16(srcB0,       LDSc + 65536 + dstW);
  gll16(srcB1,       LDSc + 65536 +  8192 + dstW);
  gll16(srcB0 + 64,  LDSc + 65536 + 16384 + dstW);
  gll16(srcB1 + 64,  LDSc + 65536 + 24576 + dstW);
  gll16(srcB0 + 128,       LDSc + 98304 + dstW);
  gll16(srcB1 + 128,       LDSc + 98304 +  8192 + dstW);
  gll16(srcB0 + 128 + 64,  LDSc + 98304 + 16384 + dstW);
  gll16(srcB1 + 128 + 64,  LDSc + 98304 + 24576 + dstW);
  asm volatile("s_waitcnt vmcnt(4)" ::: "memory");   // A(0),B(0) landed; B(1) in flight
  __builtin_amdgcn_s_barrier();

  short8 a0, a1, a2, a3, a4, a5, a6, a7;     // A quadrant: 4 m-frags x 2 kk
  short8 p0, p1, p2, p3;                     // B n0-1 x 2 kk
  short8 q0, q1, q2, q3;                     // B n2-3 x 2 kk

#define LGKM0() do {                                     \
  asm volatile("s_waitcnt lgkmcnt(0)" ::: "memory");     \
  __builtin_amdgcn_sched_barrier(0);                     \
} while (0)

#define MFMA1(M, N, A, B) \
  acc[M][N] = __builtin_amdgcn_mfma_f32_16x16x32_bf16(A, B, acc[M][N], 0, 0, 0);

  for (int t = 0; t < 16; ++t) {
    const char* Ab = LDSc + (t & 1) * 32768;
    const char* Bb = LDSc + 65536 + (t % 3) * 32768;
    char* AbN = LDSc + ((t + 1) & 1) * 32768;
    char* BbN = LDSc + 65536 + ((t + 2) % 3) * 32768;
    const int aSt = ((t + 1) & 15) * 128;
    const int bSt = ((t + 2) & 15) * 128;

    // ---- P0: read A m0-3 (kk0,kk1) + B n0-1 (kk0,kk1); stage A(T+1) kb0 ----
    a0 = *(const short8*)(Ab + aOff[0]);
    a1 = *(const short8*)(Ab + 16384 + aOff[0]);
    a2 = *(const short8*)(Ab + aOff[1]);
    a3 = *(const short8*)(Ab + 16384 + aOff[1]);
    a4 = *(const short8*)(Ab + aOff[2]);
    a5 = *(const short8*)(Ab + 16384 + aOff[2]);
    a6 = *(const short8*)(Ab + aOff[3]);
    a7 = *(const short8*)(Ab + 16384 + aOff[3]);
    p0 = *(const short8*)(Bb + bOff[0]);
    p1 = *(const short8*)(Bb + 16384 + bOff[0]);
    p2 = *(const short8*)(Bb + bOff[1]);
    p3 = *(const short8*)(Bb + 16384 + bOff[1]);
    gll16(srcA0 + aSt, AbN + dstW);
    gll16(srcA1 + aSt, AbN + 8192 + dstW);
    __builtin_amdgcn_s_barrier();
    LGKM0();
    __builtin_amdgcn_s_setprio(1);
    MFMA1(0, 0, a0, p0) MFMA1(0, 0, a1, p1) MFMA1(0, 1, a0, p2) MFMA1(0, 1, a1, p3)
    MFMA1(1, 0, a2, p0) MFMA1(1, 0, a3, p1) MFMA1(1, 1, a2, p2) MFMA1(1, 1, a3, p3)
    MFMA1(2, 0, a4, p0) MFMA1(2, 0, a5, p1) MFMA1(2, 1, a4, p2) MFMA1(2, 1, a5, p3)
    MFMA1(3, 0, a6, p0) MFMA1(3, 0, a7, p1) MFMA1(3, 1, a6, p2) MFMA1(3, 1, a7, p3)
    __builtin_amdgcn_s_setprio(0);
    __builtin_amdgcn_s_barrier();

    // ---- P1: read B n2-3; stage A(T+1) kb1 ----
    q0 = *(const short8*)(Bb + bOff[2]);
    q1 = *(const short8*)(Bb + 16384 + bOff[2]);
    q2 = *(const short8*)(Bb + bOff[3]);
    q3 = *(const short8*)(Bb + 16384 + bOff[3]);
    gll16(srcA0 + aSt + 64, AbN + 16384 + dstW);
    gll16(srcA1 + aSt + 64, AbN + 24576 + dstW);
    __builtin_amdgcn_s_barrier();
    LGKM0();
    __builtin_amdgcn_s_setprio(1);
    MFMA1(0, 2, a0, q0) MFMA1(0, 2, a1, q1) MFMA1(0, 3, a0, q2) MFMA1(0, 3, a1, q3)
    MFMA1(1, 2, a2, q0) MFMA1(1, 2, a3, q1) MFMA1(1, 3, a2, q2) MFMA1(1, 3, a3, q3)
    MFMA1(2, 2, a4, q0) MFMA1(2, 2, a5, q1) MFMA1(2, 3, a4, q2) MFMA1(2, 3, a5, q3)
    MFMA1(3, 2, a6, q0) MFMA1(3, 2, a7, q1) MFMA1(3, 3, a6, q2) MFMA1(3, 3, a7, q3)
    __builtin_amdgcn_s_setprio(0);
    __builtin_amdgcn_s_barrier();

    // ---- P2: read A m4-7; stage B(T+2) kb0 ----
    a0 = *(const short8*)(Ab + aOff[4]);
    a1 = *(const short8*)(Ab + 16384 + aOff[4]);
    a2 = *(const short8*)(Ab + aOff[5]);
    a3 = *(const short8*)(Ab + 16384 + aOff[5]);
    a4 = *(const short8*)(Ab + aOff[6]);
    a5 = *(const short8*)(Ab + 16384 + aOff[6]);
    a6 = *(const short8*)(Ab + aOff[7]);
    a7 = *(const short8*)(Ab + 16384 + aOff[7]);
    gll16(srcB0 + bSt, BbN + dstW);
    gll16(srcB1 + bSt, BbN + 8192 + dstW);
    __builtin_amdgcn_s_barrier();
    LGKM0();
    __builtin_amdgcn_s_setprio(1);
    MFMA1(4, 2, a0, q0) MFMA1(4, 2, a1, q1) MFMA1(4, 3, a0, q2) MFMA1(4, 3, a1, q3)
    MFMA1(5, 2, a2, q0) MFMA1(5, 2, a3, q1) MFMA1(5, 3, a2, q2) MFMA1(5, 3, a3, q3)
    MFMA1(6, 2, a4, q0) MFMA1(6, 2, a5, q1) MFMA1(6, 3, a4, q2) MFMA1(6, 3, a5, q3)
    MFMA1(7, 2, a6, q0) MFMA1(7, 2, a7, q1) MFMA1(7, 3, a6, q2) MFMA1(7, 3, a7, q3)
    __builtin_amdgcn_s_setprio(0);
    __builtin_amdgcn_s_barrier();

    // ---- P3: no reads (B n0-1 still live); stage B(T+2) kb1; vmcnt(4) ----
    gll16(srcB0 + bSt + 64, BbN + 16384 + dstW);
    gll16(srcB1 + bSt + 64, BbN + 24576 + dstW);
    __builtin_amdgcn_s_barrier();
    __builtin_amdgcn_s_setprio(1);
    MFMA1(4, 0, a0, p0) MFMA1(4, 0, a1, p1) MFMA1(4, 1, a0, p2) MFMA1(4, 1, a1, p3)
    MFMA1(5, 0, a2, p0) MFMA1(5, 0, a3, p1) MFMA1(5, 1, a2, p2) MFMA1(5, 1, a3, p3)
    MFMA1(6, 0, a4, p0) MFMA1(6, 0, a5, p1) MFMA1(6, 1, a4, p2) MFMA1(6, 1, a5, p3)
    MFMA1(7, 0, a6, p0) MFMA1(7, 0, a7, p1) MFMA1(7, 1, a6, p2) MFMA1(7, 1, a7, p3)
    __builtin_amdgcn_s_setprio(0);
    asm volatile("s_waitcnt vmcnt(4)" ::: "memory");
    __builtin_amdgcn_s_barrier();
  }
  asm volatile("s_waitcnt vmcnt(0)" ::: "memory");

  // epilogue: region 0 -> x_tilde (bf16), 1 -> forget, 2 -> reset
  const int region = colBase >> 10;
#pragma unroll
  for (int m = 0; m < 8; ++m) {
    int grow = rowBase + wr * 128 + m * 16 + (sl << 2);
#pragma unroll
    for (int n = 0; n < 4; ++n) {
      int gcol = colBase + wc * 64 + n * 16 + l15;
      f32x4 v = acc[m][n];
      if (region == 0) {
#pragma unroll
        for (int j = 0; j < 4; ++j)
          xtb[(size_t)(grow + j) * DDIM + gcol] = f2bf(v[j]);
      } else {
        float bv = bias[gcol - DDIM];
        unsigned short* dst = (region == 1) ? fbuf : rbuf;
        int lcol = gcol - (region << 10);
#pragma unroll
        for (int j = 0; j < 4; ++j) {
          float sg = 1.0f / (1.0f + __expf(-(v[j] + bv)));
          dst[(size_t)(grow + j) * DDIM + lcol] = f2bf(sg);
        }
      }
    }
  }
}

// ---- segmented scan (R5 versions — proven) -------------------------------

__global__ __launch_bounds__(256) void k_scan1(
    const unsigned short* __restrict__ fbuf,
    const unsigned short* __restrict__ xtb,
    float4* __restrict__ AB) {
  int chp = blockIdx.x * 256 + threadIdx.x;
  int seg = blockIdx.y;
  size_t base = (size_t)seg * SEGL * CH + chp * 2;
  const unsigned int* fp = (const unsigned int*)(fbuf + base);
  const unsigned int* xp = (const unsigned int*)(xtb + base);
  float a0 = 1.f, a1 = 1.f, b0 = 0.f, b1 = 0.f;
#pragma unroll 8
  for (int s = 0; s < SEGL; ++s) {
    unsigned int fv = fp[(size_t)s * (CH / 2)];
    unsigned int xv = xp[(size_t)s * (CH / 2)];
    float f0 = bf2f((unsigned short)fv), f1 = bf2f((unsigned short)(fv >> 16));
    float x0 = bf2f((unsigned short)xv), x1 = bf2f((unsigned short)(xv >> 16));
    b0 = (b0 - x0) * f0 + x0;  a0 *= f0;
    b1 = (b1 - x1) * f1 + x1;  a1 *= f1;
  }
  AB[(size_t)seg * (CH / 2) + chp] = (float4){a0, b0, a1, b1};
}

__global__ __launch_bounds__(256) void k_scan2(
    const float* __restrict__ c0,
    const float4* __restrict__ AB,
    float* __restrict__ Cin,
    float* __restrict__ clast) {
  int chp = blockIdx.x * 256 + threadIdx.x;
  float2 cc = ((const float2*)c0)[chp];
  float ca = cc.x, cb = cc.y;
#pragma unroll
  for (int s = 0; s < NSEG; ++s) {
    ((float2*)Cin)[(size_t)s * (CH / 2) + chp] = (float2){ca, cb};
    float4 ab = AB[(size_t)s * (CH / 2) + chp];
    ca = ca * ab.x + ab.y;
    cb = cb * ab.z + ab.w;
  }
  ((float2*)clast)[chp] = (float2){ca, cb};
}

__global__ __launch_bounds__(256) void k_scan3(
    const float* __restrict__ x,
    const unsigned short* __restrict__ fbuf,
    const unsigned short* __restrict__ xtb,
    const unsigned short* __restrict__ rbuf,
    const float* __restrict__ Cin,
    float* __restrict__ h) {
  int chp = blockIdx.x * 256 + threadIdx.x;
  int seg = blockIdx.y;
  float2 cc = ((const float2*)Cin)[(size_t)seg * (CH / 2) + chp];
  float ca = cc.x, cb = cc.y;
  size_t base = (size_t)seg * SEGL * CH + chp * 2;
  const unsigned int* fp = (const unsigned int*)(fbuf + base);
  const unsigned int* tp = (const unsigned int*)(xtb + base);
  const unsigned int* rp = (const unsigned int*)(rbuf + base);
  const float2* xp = (const float2*)(x + base);
  float2* hp = (float2*)(h + base);
#pragma unroll 4
  for (int s = 0; s < SEGL; ++s) {
    unsigned int fv = fp[(size_t)s * (CH / 2)];
    unsigned int tv = tp[(size_t)s * (CH / 2)];
    unsigned int rv = rp[(size_t)s * (CH / 2)];
    float2 xv = xp[(size_t)s * (CH / 2)];
    float f0 = bf2f((unsigned short)fv), f1 = bf2f((unsigned short)(fv >> 16));
    float t0 = bf2f((unsigned short)tv), t1 = bf2f((unsigned short)(tv >> 16));
    float r0 = bf2f((unsigned short)rv), r1 = bf2f((unsigned short)(rv >> 16));
    ca = (ca - t0) * f0 + t0;
    cb = (cb - t1) * f1 + t1;
    float e0 = __expf(-2.f * fabsf(ca));
    float e1 = __expf(-2.f * fabsf(cb));
    float g0 = copysignf((1.f - e0) / (1.f + e0), ca);
    float g1 = copysignf((1.f - e1) / (1.f + e1), cb);
    float h0 = (g0 - xv.x) * r0 + xv.x;
    float h1 = (g1 - xv.y) * r1 + xv.y;
    hp[(size_t)s * (CH / 2)] = (float2){h0, h1};
  }
}

// ---- launch --------------------------------------------------------------

extern "C" void kernel_launch(void* const* d_in, const int* in_sizes, int n_in,
                              void* d_out, int out_size, void* d_ws, size_t ws_size,
                              hipStream_t stream) {
  const float* x    = (const float*)d_in[0];
  const float* w    = (const float*)d_in[1];
  const float* bias = (const float*)d_in[2];
  const float* c0   = (const float*)d_in[3];
  float* out = (float*)d_out;
  char* ws = (char*)d_ws;

  unsigned short* wb   = (unsigned short*)(ws);
  float4*         AB   = (float4*)(ws);
  float*          Cin  = (float*)(ws + 4194304);
  unsigned short* xtb  = (unsigned short*)(ws + 6291456);
  unsigned short* fbuf = (unsigned short*)(ws + 73400320);
  unsigned short* rbuf = (unsigned short*)(ws + 140509184);
  unsigned short* xb = (unsigned short*)d_out;   // h-region, dead until scan3

  k_convert_x<<<2048, 256, 0, stream>>>((const float4*)x, (ushort4*)xb, MDIM * KDIM / 4);
  k_convert_w<<<(NDIM * KDIM) / 256, 256, 0, stream>>>(w, wb);

  k_gemm256<<<1536, 512, 0, stream>>>(xb, wb, bias, xtb, fbuf, rbuf);

  k_scan1<<<dim3(32, NSEG), 256, 0, stream>>>(fbuf, xtb, AB);
  k_scan2<<<32, 256, 0, stream>>>(c0, AB, Cin, out + (size_t)L_SEQ * CH);
  k_scan3<<<dim3(32, NSEG), 256, 0, stream>>>(x, fbuf, xtb, rbuf, Cin, out);
}